// Round 1
// baseline (461.206 us; speedup 1.0000x reference)
//
#include <hip/hip_runtime.h>

typedef __bf16 bf16x8 __attribute__((ext_vector_type(8)));
typedef float f32x4 __attribute__((ext_vector_type(4)));

#define B_ 2
#define T_ 2048
#define D_ 1024
#define H_ 16

__device__ __forceinline__ ushort f2bf(float f) {
  union { float f; unsigned u; } v; v.f = f;
  unsigned u = v.u;
  return (ushort)((u + 0x7FFFu + ((u >> 16) & 1u)) >> 16);
}

// ---------------- cast x -> bf16 ----------------
__global__ __launch_bounds__(256) void cvt_kernel(const float* __restrict__ in,
                                                  ushort* __restrict__ out) {
  int i = (blockIdx.x * 256 + threadIdx.x) * 4;
  float4 v = *(const float4*)(in + i);
  ushort4 o;
  o.x = f2bf(v.x); o.y = f2bf(v.y); o.z = f2bf(v.z); o.w = f2bf(v.w);
  *(ushort4*)(out + i) = o;
}

// ---------------- transpose + cast: in[R][C] f32 -> out[C][R] bf16 ----------------
__global__ void transpose_cvt(const float* __restrict__ in, ushort* __restrict__ out,
                              int R, int C) {
  __shared__ float tile[32][33];
  int bx = blockIdx.x * 32, by = blockIdx.y * 32;
  int tx = threadIdx.x, ty = threadIdx.y;  // block (32,8)
  for (int i = 0; i < 32; i += 8)
    tile[ty + i][tx] = in[(size_t)(by + ty + i) * C + (bx + tx)];
  __syncthreads();
  for (int i = 0; i < 32; i += 8)
    out[(size_t)(bx + ty + i) * R + (by + tx)] = f2bf(tile[tx][ty + i]);
}

// ---------------- bf16 GEMM: C[M,N] = A[M,K] * BT[N,K]^T (+bias) ----------------
__global__ __launch_bounds__(256) void gemm_bf16(
    const ushort* __restrict__ A, const ushort* __restrict__ BT,
    float* __restrict__ C, const float* __restrict__ bias,
    int M, int N, int K) {
  __shared__ ushort As[128 * 40];
  __shared__ ushort Bs[128 * 40];
  int tid = threadIdx.x;
  int wave = tid >> 6, lane = tid & 63;
  int l16 = lane & 15, lhi = lane >> 4;
  int m0 = blockIdx.y * 128, n0 = blockIdx.x * 128;
  int wr = (wave >> 1) * 64, wc = (wave & 1) * 64;
  f32x4 acc[4][4] = {};
  for (int kk = 0; kk < K; kk += 32) {
    __syncthreads();
    for (int i = 0; i < 2; ++i) {
      int e = tid + i * 256;          // 0..511
      int row = e >> 2, ch = e & 3;   // 128 rows x 4 chunks of 8 bf16
      *(int4*)(As + row * 40 + ch * 8) =
          *(const int4*)(A + (size_t)(m0 + row) * K + kk + ch * 8);
      *(int4*)(Bs + row * 40 + ch * 8) =
          *(const int4*)(BT + (size_t)(n0 + row) * K + kk + ch * 8);
    }
    __syncthreads();
    bf16x8 af[4], bfr[4];
    for (int f = 0; f < 4; ++f)
      af[f] = *(const bf16x8*)(As + (wr + f * 16 + l16) * 40 + lhi * 8);
    for (int f = 0; f < 4; ++f)
      bfr[f] = *(const bf16x8*)(Bs + (wc + f * 16 + l16) * 40 + lhi * 8);
    for (int fm = 0; fm < 4; ++fm)
      for (int fn = 0; fn < 4; ++fn)
        acc[fm][fn] = __builtin_amdgcn_mfma_f32_16x16x32_bf16(af[fm], bfr[fn], acc[fm][fn], 0, 0, 0);
  }
  for (int fm = 0; fm < 4; ++fm)
    for (int fn = 0; fn < 4; ++fn)
      for (int r = 0; r < 4; ++r) {
        int row = m0 + wr + fm * 16 + lhi * 4 + r;
        int col = n0 + wc + fn * 16 + l16;
        float v = acc[fm][fn][r];
        if (bias) v += bias[col];
        C[(size_t)row * N + col] = v;
      }
}

// ---------------- build Qaug/Kaug/V from qkv ----------------
// Qaug[bh,t,0:64]  = q/8 ;  Qaug[bh,t,64+2m] = (qs*sin(tw)+qc*cos(tw))/8,
// Qaug[bh,t,64+2m+1] = (qc*sin(tw)-qs*cos(tw))/8
// Kaug[bh,t,0:64]  = k   ;  Kaug[bh,t,64+2m] = cos(tw), [..+1] = sin(tw)
__global__ __launch_bounds__(256) void augment_kernel(
    const float* __restrict__ qkv,  // [B*T, 3072]
    ushort* __restrict__ Qaug, ushort* __restrict__ Kaug, ushort* __restrict__ Vb) {
  int row = blockIdx.x;  // b*T + t
  int b = row >> 11;
  int t = row & 2047;
  int tid = threadIdx.x;
  const float* src = qkv + (size_t)row * 3072;
  for (int i = 0; i < 4; ++i) {
    int idx = tid + i * 256;  // 0..1023
    int h = idx >> 6, d = idx & 63;
    size_t obase = ((size_t)(b * H_ + h) * T_ + t);
    float q = src[idx];
    float k = src[1024 + idx];
    float v = src[2048 + idx];
    Qaug[obase * 128 + d] = f2bf(q * 0.125f);
    Kaug[obase * 128 + d] = f2bf(k);
    Vb[obase * 64 + d] = f2bf(v);
  }
  for (int i = 0; i < 2; ++i) {
    int idx = tid + i * 256;  // 0..511
    int h = idx >> 5, mm = idx & 31;
    int gdim = h * 64 + 2 * mm;
    float w = expf(-9.2103403719761836f * (float)gdim * (1.0f / 1024.0f));
    float ang = w * (float)t;
    float si = sinf(ang), co = cosf(ang);
    float qs = src[h * 64 + 2 * mm], qc = src[h * 64 + 2 * mm + 1];
    size_t obase = ((size_t)(b * H_ + h) * T_ + t);
    Qaug[obase * 128 + 64 + 2 * mm]     = f2bf((qs * si + qc * co) * 0.125f);
    Qaug[obase * 128 + 64 + 2 * mm + 1] = f2bf((qc * si - qs * co) * 0.125f);
    Kaug[obase * 128 + 64 + 2 * mm]     = f2bf(co);
    Kaug[obase * 128 + 64 + 2 * mm + 1] = f2bf(si);
  }
}

// ---------------- fused causal attention with score output ----------------
__global__ __launch_bounds__(256) void attn_kernel(
    const ushort* __restrict__ Qaug,  // [BH, T, 128]
    const ushort* __restrict__ Kaug,  // [BH, T, 128]
    const ushort* __restrict__ Vb,    // [BH, T, 64]
    float* __restrict__ score,        // [BH, T, T]
    ushort* __restrict__ ctxb) {      // [B*T, 1024] bf16
  int qt = blockIdx.x;   // 0..31
  int bh = blockIdx.y;   // 0..31
  int tid = threadIdx.x;
  int wave = tid >> 6, lane = tid & 63;
  int l16 = lane & 15, lhi = lane >> 4;
  int qrow_base = wave * 16;

  __shared__ ushort Qs[64 * 136];
  __shared__ ushort Ks[64 * 136];
  __shared__ ushort VsT[64 * 72];  // [dim][key]
  __shared__ ushort Ps[64 * 72];   // [qrow][key]

  const ushort* Qg = Qaug + ((size_t)bh * T_ + qt * 64) * 128;
  for (int i = 0; i < 4; ++i) {
    int e = tid + i * 256;            // 0..1023
    int row = e >> 4, chunk = e & 15; // 64 rows x 16 chunks of 8
    *(int4*)(Qs + row * 136 + chunk * 8) = *(const int4*)(Qg + row * 128 + chunk * 8);
  }

  float m[4], l[4];
  for (int r = 0; r < 4; ++r) { m[r] = -1e30f; l[r] = 0.f; }
  f32x4 zero4 = {0.f, 0.f, 0.f, 0.f};

  // ---- sweep 1: online max/sum ----
  for (int kt = 0; kt <= qt; ++kt) {
    __syncthreads();
    const ushort* Kg = Kaug + ((size_t)bh * T_ + kt * 64) * 128;
    for (int i = 0; i < 4; ++i) {
      int e = tid + i * 256;
      int row = e >> 4, chunk = e & 15;
      *(int4*)(Ks + row * 136 + chunk * 8) = *(const int4*)(Kg + row * 128 + chunk * 8);
    }
    __syncthreads();
    f32x4 s[4];
    for (int f = 0; f < 4; ++f) s[f] = zero4;
    for (int ks = 0; ks < 4; ++ks) {
      bf16x8 af = *(const bf16x8*)(Qs + (qrow_base + l16) * 136 + ks * 32 + lhi * 8);
      for (int fn = 0; fn < 4; ++fn) {
        bf16x8 bfr = *(const bf16x8*)(Ks + (fn * 16 + l16) * 136 + ks * 32 + lhi * 8);
        s[fn] = __builtin_amdgcn_mfma_f32_16x16x32_bf16(af, bfr, s[fn], 0, 0, 0);
      }
    }
    if (kt == qt) {
      for (int fn = 0; fn < 4; ++fn)
        for (int r = 0; r < 4; ++r) {
          int gi = qt * 64 + qrow_base + lhi * 4 + r;
          int gj = kt * 64 + fn * 16 + l16;
          if (gj > gi) s[fn][r] = -1e30f;
        }
    }
    for (int r = 0; r < 4; ++r) {
      float mx = fmaxf(fmaxf(s[0][r], s[1][r]), fmaxf(s[2][r], s[3][r]));
      for (int dd = 1; dd < 16; dd <<= 1) mx = fmaxf(mx, __shfl_xor(mx, dd));
      float mn = fmaxf(m[r], mx);
      float sum = 0.f;
      for (int fn = 0; fn < 4; ++fn) sum += __expf(s[fn][r] - mn);
      for (int dd = 1; dd < 16; dd <<= 1) sum += __shfl_xor(sum, dd);
      l[r] = l[r] * __expf(m[r] - mn) + sum;
      m[r] = mn;
    }
  }

  float invl[4];
  for (int r = 0; r < 4; ++r) invl[r] = 1.f / l[r];
  f32x4 cacc[4];
  for (int f = 0; f < 4; ++f) cacc[f] = zero4;

  float* srow = score + ((size_t)bh * T_ + (size_t)qt * 64) * T_;

  // ---- sweep 2: P, score write, ctx accumulate ----
  for (int kt = 0; kt <= qt; ++kt) {
    __syncthreads();
    const ushort* Kg = Kaug + ((size_t)bh * T_ + kt * 64) * 128;
    for (int i = 0; i < 4; ++i) {
      int e = tid + i * 256;
      int row = e >> 4, chunk = e & 15;
      *(int4*)(Ks + row * 136 + chunk * 8) = *(const int4*)(Kg + row * 128 + chunk * 8);
    }
    const ushort* Vg = Vb + ((size_t)bh * T_ + kt * 64) * 64;
    for (int i = 0; i < 2; ++i) {
      int e = tid + i * 256;          // 0..511
      int j = e >> 3, dc = e & 7;
      union { int4 v; ushort u[8]; } pk;
      pk.v = *(const int4*)(Vg + j * 64 + dc * 8);
      for (int u = 0; u < 8; ++u) VsT[(dc * 8 + u) * 72 + j] = pk.u[u];
    }
    __syncthreads();
    f32x4 s[4];
    for (int f = 0; f < 4; ++f) s[f] = zero4;
    for (int ks = 0; ks < 4; ++ks) {
      bf16x8 af = *(const bf16x8*)(Qs + (qrow_base + l16) * 136 + ks * 32 + lhi * 8);
      for (int fn = 0; fn < 4; ++fn) {
        bf16x8 bfr = *(const bf16x8*)(Ks + (fn * 16 + l16) * 136 + ks * 32 + lhi * 8);
        s[fn] = __builtin_amdgcn_mfma_f32_16x16x32_bf16(af, bfr, s[fn], 0, 0, 0);
      }
    }
    if (kt == qt) {
      for (int fn = 0; fn < 4; ++fn)
        for (int r = 0; r < 4; ++r) {
          int gi = qt * 64 + qrow_base + lhi * 4 + r;
          int gj = kt * 64 + fn * 16 + l16;
          if (gj > gi) s[fn][r] = -1e30f;
        }
    }
    for (int fn = 0; fn < 4; ++fn)
      for (int r = 0; r < 4; ++r) {
        int gi_loc = qrow_base + lhi * 4 + r;
        int gj = kt * 64 + fn * 16 + l16;
        float p = __expf(s[fn][r] - m[r]) * invl[r];
        srow[(size_t)gi_loc * T_ + gj] = p;
        Ps[gi_loc * 72 + fn * 16 + l16] = f2bf(p);
      }
    __syncthreads();
    for (int ks = 0; ks < 2; ++ks) {
      bf16x8 pa = *(const bf16x8*)(Ps + (qrow_base + l16) * 72 + ks * 32 + lhi * 8);
      for (int fn = 0; fn < 4; ++fn) {
        bf16x8 vbf = *(const bf16x8*)(VsT + (fn * 16 + l16) * 72 + ks * 32 + lhi * 8);
        cacc[fn] = __builtin_amdgcn_mfma_f32_16x16x32_bf16(pa, vbf, cacc[fn], 0, 0, 0);
      }
    }
  }

  // zero-fill upper-triangle tiles of score
  {
    int row = tid >> 2, c16 = (tid & 3) * 16;
    float4 z = {0.f, 0.f, 0.f, 0.f};
    for (int kt = qt + 1; kt < 32; ++kt) {
      float* dst = srow + (size_t)row * T_ + kt * 64 + c16;
      for (int u = 0; u < 4; ++u) ((float4*)dst)[u] = z;
    }
  }

  // write ctx (bf16) into [B*T, 1024]
  int b = bh >> 4, h = bh & 15;
  for (int fn = 0; fn < 4; ++fn)
    for (int r = 0; r < 4; ++r) {
      int t = qt * 64 + qrow_base + lhi * 4 + r;
      int col = h * 64 + fn * 16 + l16;
      ctxb[((size_t)(b * T_ + t)) * 1024 + col] = f2bf(cacc[fn][r]);
    }
}

extern "C" void kernel_launch(void* const* d_in, const int* in_sizes, int n_in,
                              void* d_out, int out_size, void* d_ws, size_t ws_size,
                              hipStream_t stream) {
  const float* x    = (const float*)d_in[0];
  // d_in[1] = mask : causal by construction, handled analytically
  const float* Wqkv = (const float*)d_in[2];
  const float* Wout = (const float*)d_in[3];
  const float* bout = (const float*)d_in[4];

  char* ws = (char*)d_ws;
  ushort* xb    = (ushort*)(ws + 0);           //  8 MB
  ushort* wqkvT = (ushort*)(ws + 8388608);     //  6 MB
  ushort* woutT = (ushort*)(ws + 14680064);    //  2 MB
  float*  qkv   = (float*) (ws + 16777216);    // 48 MB
  ushort* Qaug  = (ushort*)(ws + 67108864);    // 16 MB
  ushort* Kaug  = (ushort*)(ws + 83886080);    // 16 MB
  ushort* Vb    = (ushort*)(ws + 100663296);   //  8 MB
  ushort* ctxb  = (ushort*)(ws + 109051904);   //  8 MB

  float* out   = (float*)d_out;
  float* score = out + (size_t)4194304;  // B*T*D floats, then [B,H,T,T]

  cvt_kernel<<<4096, 256, 0, stream>>>(x, xb);
  dim3 tb(32, 8);
  transpose_cvt<<<dim3(3072 / 32, 1024 / 32), tb, 0, stream>>>(Wqkv, wqkvT, 1024, 3072);
  transpose_cvt<<<dim3(1024 / 32, 1024 / 32), tb, 0, stream>>>(Wout, woutT, 1024, 1024);
  gemm_bf16<<<dim3(24, 32), 256, 0, stream>>>(xb, wqkvT, qkv, nullptr, 4096, 3072, 1024);
  augment_kernel<<<4096, 256, 0, stream>>>(qkv, Qaug, Kaug, Vb);
  attn_kernel<<<dim3(32, 32), 256, 0, stream>>>(Qaug, Kaug, Vb, score, ctxb);
  gemm_bf16<<<dim3(8, 32), 256, 0, stream>>>(ctxb, woutT, out, bout, 4096, 1024, 1024);
}